// Round 3
// baseline (679.567 us; speedup 1.0000x reference)
//
#include <hip/hip_runtime.h>

// TreecrfLossSRL: inside algorithm, B=64, N=256. Two CYK charts per batch
// (ob / allv) -> scalar (logz - marg).sum()/denom.
//
// LINEAR-DOMAIN chart with per-column scalar scale:
// chart col v stores X[v][i] = 2^(A[i,v] - cmax[v]), cmax[v] = exact max_i.
// Level-w term = s_u * X[u][i] * X[w-u][i+u], s_u = 2^(cmax[u]+cmax[w-u]-base_w)
// wave-uniform -> inner loop is pure mul+fma (no per-term exp2/max).
// Cross-wave combine is ATOMIC-FREE (r2 -> r3: suspected flat-atomic-on-LDS
// container fault): two-stage deterministic slots. Waves 8..15 STORE partials
// into 8 per-entry slots; barrier; waves 0..7 ADD theirs (one owner per slot
// per stage, race-free); barrier; finalize sums 8 slots with plain adds, adds
// D + base + log2(sum), then a cross-wave max-reduce fixes cmax[w] and a short
// pass converts col w to X. PAIRED LEVELS (w, w+1) share the left operand
// (3 LDS reads / 2 terms); level w+1's u=1 and u=w terms (need col w) fold
// into its finalize with a scalar rescale from the provisional base.
// All chart/scr accesses stride-1 across lanes (conflict-free, r6-proven
// address skeleton kept verbatim). LDS = 149,008 B.

#define NN 256
#define BATCH 64
#define NCHART (2 * BATCH)
#define NEGV -1000000000.0f
#define NEGB -1.0e30f
#define K2f 1.4426950408889634f   /* log2(e) */
#define LN2f 0.6931471805599453f

#define CHARTF 32896                   /* triangular chart, no padding */
#define CMAXF 260                      /* cmax[257] + pad */
#define SCR_OFF (CHARTF + CMAXF)
#define SCRF 4096                      /* >= 8*(E0+E1) max = 4008 at w=6 */
#define LDSF (SCR_OFF + SCRF)          /* 37252 floats = 149008 B */

#define RES_OFF ((size_t)16)
#define LEN_OFF ((size_t)(16 + NCHART))
#define FB_OFF  ((size_t)(16 + NCHART + BATCH + 16))

__device__ __forceinline__ float fexp2(float x) {
#if __has_builtin(__builtin_amdgcn_exp2f)
    return __builtin_amdgcn_exp2f(x);
#else
    return exp2f(x);
#endif
}

// column start (floats) for width v, v in 1..256
__device__ __forceinline__ int cstart(int v) {
    return 257 * (v - 1) - ((v * (v - 1)) >> 1);
}

// natural-log score at span [i, j] for type t (0 = ob/constrained, 1 = allv)
__device__ __forceinline__ float score_at(const float* __restrict__ logits,
                                          const int* __restrict__ spans_ind,
                                          const void* __restrict__ span_mask,
                                          int isb, int t, int b, int i, int j) {
    size_t sidx = ((size_t)b * NN + i) * NN + j;
    float l0 = logits[2 * sidx];
    float l1 = logits[2 * sidx + 1];
    if (t) {
        float mx = fmaxf(l0, l1), mn = fminf(l0, l1);
        return mx + log1pf(__expf(mn - mx));
    } else {
        bool sind = (spans_ind[sidx] == 2);
        bool sm = isb ? (((const unsigned char*)span_mask)[sidx] != 0)
                      : (((const int*)span_mask)[sidx] != 0);
        float s0 = (sm || sind)  ? NEGV : l0;
        float s1 = (sm || !sind) ? NEGV : l1;
        float mx = fmaxf(s0, s1), mn = fminf(s0, s1);
        return mx + log1pf(__expf(mn - mx));
    }
}

// paired levels (w, w+1), compile-time KK = ceil(E0/64)
template <int KK>
__device__ __forceinline__ void level_pair(
    float* __restrict__ Lc, float* __restrict__ scr, float* __restrict__ cm,
    float* __restrict__ swm, float* __restrict__ sres,
    int w, int tid, int wave, int lane, int lenv) {
    const int T = w - 1;
    const int E0 = NN + 1 - w;
    const int E1 = NN - w;
    float* __restrict__ scr0 = scr;            // 8 slots x E0
    float* __restrict__ scr1 = scr + 8 * E0;   // 8 slots x E1

    // wave-parallel base scan: b0 = base for level w (u in 1..w-1),
    // b1 = provisional base for level w+1 (u in 2..w-1; u=1,w folded later)
    float b0 = NEGB, b1 = NEGB;
    for (int uu = 1 + lane; uu <= T; uu += 64) {
        float cu = cm[uu];
        b0 = fmaxf(b0, cu + cm[w - uu]);
        if (uu >= 2) b1 = fmaxf(b1, cu + cm[w + 1 - uu]);
    }
    for (int d = 32; d; d >>= 1) {
        b0 = fmaxf(b0, __shfl_xor(b0, d));
        b1 = fmaxf(b1, __shfl_xor(b1, d));
    }

    const int C = (T + 15) >> 4;
    const int u0 = 1 + wave * C;
    const int u1 = min(u0 + C, w);
    int steps = u1 - u0;

    float acc0[KK], acc1[KK];
#pragma unroll
    for (int k = 0; k < KK; ++k) { acc0[k] = 0.f; acc1[k] = 0.f; }

    if (steps > 0) {
        int u = u0, v = w - u0;
        int la  = cstart(u) + lane;
        int ra0 = cstart(v) + u + lane;
        int ra1 = cstart(v + 1) + u + lane;
        int A = 257 - u;   // la stride (decrementing per u)
        int B = 257 - v;   // ra0 stride (incrementing per u)

        if (u == 1) {      // level-w-only term at u = 1 (wave 0 only)
            float su = fexp2(cm[1] + cm[w - 1] - b0);
#pragma unroll
            for (int k = 0; k < KK; ++k) {
                float t0 = su * Lc[la + 64 * k];
                acc0[k] = fmaf(t0, Lc[ra0 + 64 * k], acc0[k]);
            }
            la += A; A -= 1;
            ra0 -= B; ra1 -= B - 1; B += 1;
            ++u; --steps;
        }

        for (int it = steps >> 2; it > 0; --it) {
            float cj0 = cm[u], cj1 = cm[u + 1], cj2 = cm[u + 2], cj3 = cm[u + 3];
            float d0 = cm[w + 1 - u], d1 = cm[w - u], d2 = cm[w - 1 - u],
                  d3 = cm[w - 2 - u], d4 = cm[w - 3 - u];
            float s00 = fexp2(cj0 + d1 - b0), s01 = fexp2(cj1 + d2 - b0),
                  s02 = fexp2(cj2 + d3 - b0), s03 = fexp2(cj3 + d4 - b0);
            float s10 = fexp2(cj0 + d0 - b1), s11 = fexp2(cj1 + d1 - b1),
                  s12 = fexp2(cj2 + d2 - b1), s13 = fexp2(cj3 + d3 - b1);
            const int la1 = la + A, la2 = la1 + A - 1, la3 = la2 + A - 2;
            const int rb0 = ra0 - B, rc0 = rb0 - B - 1, rd0 = rc0 - B - 2;
            const int rb1 = ra1 - (B - 1), rc1 = rb1 - B, rd1 = rc1 - B - 1;
            float l[KK][4], r0[KK][4], r1[KK][4];
#pragma unroll
            for (int k = 0; k < KK; ++k) {
                l[k][0] = Lc[la  + 64 * k]; l[k][1] = Lc[la1 + 64 * k];
                l[k][2] = Lc[la2 + 64 * k]; l[k][3] = Lc[la3 + 64 * k];
                r0[k][0] = Lc[ra0 + 64 * k]; r0[k][1] = Lc[rb0 + 64 * k];
                r0[k][2] = Lc[rc0 + 64 * k]; r0[k][3] = Lc[rd0 + 64 * k];
                r1[k][0] = Lc[ra1 + 64 * k]; r1[k][1] = Lc[rb1 + 64 * k];
                r1[k][2] = Lc[rc1 + 64 * k]; r1[k][3] = Lc[rd1 + 64 * k];
            }
#pragma unroll
            for (int k = 0; k < KK; ++k) {
                acc0[k] = fmaf(s00 * l[k][0], r0[k][0], acc0[k]);
                acc0[k] = fmaf(s01 * l[k][1], r0[k][1], acc0[k]);
                acc0[k] = fmaf(s02 * l[k][2], r0[k][2], acc0[k]);
                acc0[k] = fmaf(s03 * l[k][3], r0[k][3], acc0[k]);
                acc1[k] = fmaf(s10 * l[k][0], r1[k][0], acc1[k]);
                acc1[k] = fmaf(s11 * l[k][1], r1[k][1], acc1[k]);
                acc1[k] = fmaf(s12 * l[k][2], r1[k][2], acc1[k]);
                acc1[k] = fmaf(s13 * l[k][3], r1[k][3], acc1[k]);
            }
            la = la3 + (A - 3); A -= 4;
            ra0 = rd0 - (B + 3);
            ra1 = rd1 - (B + 2); B += 4;
            u += 4;
        }
        for (int rem = steps & 3; rem > 0; --rem) {
            float cu = cm[u];
            float su0 = fexp2(cu + cm[w - u] - b0);
            float su1 = fexp2(cu + cm[w + 1 - u] - b1);
#pragma unroll
            for (int k = 0; k < KK; ++k) {
                float lv = Lc[la + 64 * k];
                acc0[k] = fmaf(su0 * lv, Lc[ra0 + 64 * k], acc0[k]);
                acc1[k] = fmaf(su1 * lv, Lc[ra1 + 64 * k], acc1[k]);
            }
            la += A; A -= 1;
            ra0 -= B; ra1 -= B - 1; B += 1;
            ++u;
        }
    }

    // stage 1: waves 8..15 store partials into slot (wave-8)
    if (wave >= 8) {
        const int sl = wave - 8;
#pragma unroll
        for (int k = 0; k < KK; ++k) {
            int g = lane + 64 * k;
            if (g < E0) scr0[sl * E0 + g] = acc0[k];
            if (g < E1) scr1[sl * E1 + g] = acc1[k];
        }
    }
    __syncthreads();   // B0: slots initialized
    // stage 2: waves 0..7 accumulate into their slot (race-free RMW)
    if (wave < 8) {
#pragma unroll
        for (int k = 0; k < KK; ++k) {
            int g = lane + 64 * k;
            if (g < E0) scr0[wave * E0 + g] += acc0[k];
            if (g < E1) scr1[wave * E1 + g] += acc1[k];
        }
    }
    __syncthreads();   // B1: partials complete

    // F_lo: combine 8 slots, finalize col w in log2 domain, wave maxima
    {
        float a = NEGB;
        if (tid < E0) {
            float s = ((scr0[tid]          + scr0[tid + E0])     +
                       (scr0[tid + 2 * E0] + scr0[tid + 3 * E0])) +
                      ((scr0[tid + 4 * E0] + scr0[tid + 5 * E0]) +
                       (scr0[tid + 6 * E0] + scr0[tid + 7 * E0]));
            int ad = cstart(w) + tid;
            a = Lc[ad] + b0 + __log2f(s);   // Lc[ad] held K2f*D
            Lc[ad] = a;                     // temp: log2-domain A
            if (tid == 0 && w == lenv) *sres = a;
        }
        float m = a;
        for (int d = 32; d; d >>= 1) m = fmaxf(m, __shfl_xor(m, d));
        if (lane == 0) swm[wave] = m;
    }
    __syncthreads();   // B2
    float cmw;
    {
        float m = swm[0];
#pragma unroll
        for (int i = 1; i < 16; ++i) m = fmaxf(m, swm[i]);
        cmw = m;
        if (tid < E0) {
            int ad = cstart(w) + tid;
            Lc[ad] = fexp2(Lc[ad] - cmw);   // convert col w to X
        }
        if (tid == 0) cm[w] = cmw;
    }
    __syncthreads();   // B3: col w X visible for hi's folded terms

    // F_hi: combine 8 slots + folded u=1 / u=w terms, finalize col w+1
    {
        float a = NEGB;
        float bb = fmaxf(b1, cm[1] + cmw);
        if (tid < E1) {
            float s = ((scr1[tid]          + scr1[tid + E1])     +
                       (scr1[tid + 2 * E1] + scr1[tid + 3 * E1])) +
                      ((scr1[tid + 4 * E1] + scr1[tid + 5 * E1]) +
                       (scr1[tid + 6 * E1] + scr1[tid + 7 * E1]));
            float sc = fexp2(b1 - bb);
            float sf = fexp2(cm[1] + cmw - bb);
            int cw = cstart(w);
            float tA = Lc[tid] * Lc[cw + tid + 1];   // X1[i]   * Xw[i+1]
            float tB = Lc[cw + tid] * Lc[tid + w];   // Xw[i]   * X1[i+w]
            float tot = fmaf(s, sc, (tA + tB) * sf);
            int ad = cstart(w + 1) + tid;
            a = Lc[ad] + bb + __log2f(tot);
            Lc[ad] = a;
            if (tid == 0 && (w + 1) == lenv) *sres = a;
        }
        float m = a;
        for (int d = 32; d; d >>= 1) m = fmaxf(m, __shfl_xor(m, d));
        if (lane == 0) swm[wave] = m;
    }
    __syncthreads();   // B4
    {
        float m = swm[0];
#pragma unroll
        for (int i = 1; i < 16; ++i) m = fmaxf(m, swm[i]);
        if (tid < E1) {
            int ad = cstart(w + 1) + tid;
            Lc[ad] = fexp2(Lc[ad] - m);
        }
        if (tid == 0) cm[w + 1] = m;
    }
    __syncthreads();   // B5: col w+1 X visible
}

// small-E path (w >= 194, E <= 63): sub-grouped u-split (r9 skeleton),
// deterministic 16-slot scratch (no atomics)
__device__ __forceinline__ void level_small(
    float* __restrict__ Lc, float* __restrict__ scr, float* __restrict__ cm,
    float* __restrict__ sres,
    int w, int tid, int wave, int lane, int lenv) {
    const int T = w - 1;
    const int E = NN + 1 - w;

    float b0 = NEGB;
    for (int uu = 1 + lane; uu <= T; uu += 64)
        b0 = fmaxf(b0, cm[uu] + cm[w - uu]);
    for (int d = 32; d; d >>= 1) b0 = fmaxf(b0, __shfl_xor(b0, d));

    const int EH = (E <= 1) ? 1 : (1 << (32 - __clz(E - 1)));  // pow2 >= E
    const int sh2 = (EH == 1) ? 0 : (31 - __clz(EH));
    const int g = lane & (EH - 1);
    const int slot = (wave << (6 - sh2)) + (lane >> sh2);
    const int slots_sh = 10 - sh2;
    const int C = (T + (1 << slots_sh) - 1) >> slots_sh;
    const int u0 = 1 + slot * C;
    const int u1 = min(u0 + C, w);
    const int steps = u1 - u0;

    float acc = 0.f;
    if (steps > 0) {
        const int v0 = w - u0;
        int la = cstart(u0) + g;
        int ra = cstart(v0) + g + u0;
        int A = 257 - u0;
        int B = 257 - v0;
        int u = u0;
        for (int it = steps; it > 0; --it) {
            float su = fexp2(cm[u] + cm[w - u] - b0);
            acc = fmaf(su * Lc[la], Lc[ra], acc);
            la += A; A -= 1;
            ra -= B; B += 1;
            ++u;
        }
    }
    for (int d = 32; d >= EH; d >>= 1) acc += __shfl_xor(acc, d);
    if ((lane >> sh2) == 0) scr[wave * EH + g] = acc;   // 16 slots x EH
    __syncthreads();
    if (tid < 64) {     // finalize + cmax + convert entirely in wave 0
        float a = NEGB;
        if (tid < E) {
            float s = 0.f;
#pragma unroll
            for (int sl = 0; sl < 16; ++sl) s += scr[sl * EH + tid];
            a = Lc[cstart(w) + tid] + b0 + __log2f(s);
            if (tid == 0 && w == lenv) *sres = a;
        }
        float m = a;
        for (int d = 32; d; d >>= 1) m = fmaxf(m, __shfl_xor(m, d));
        if (tid < E) Lc[cstart(w) + tid] = fexp2(a - m);
        if (tid == 0) cm[w] = m;
    }
    __syncthreads();
}

// direct path for w in [2,5]: each thread does its entry's full sum
__device__ __forceinline__ void level_direct(
    float* __restrict__ Lc, float* __restrict__ cm,
    float* __restrict__ swm, float* __restrict__ sres,
    int w, int tid, int wave, int lane, int lenv) {
    const int E = NN + 1 - w;
    float a = NEGB;
    if (tid < E) {
        float b0 = NEGB;
        for (int u = 1; u <= w - 1; ++u) b0 = fmaxf(b0, cm[u] + cm[w - u]);
        float s = 0.f;
        for (int u = 1; u <= w - 1; ++u) {
            float su = fexp2(cm[u] + cm[w - u] - b0);
            s = fmaf(su * Lc[cstart(u) + tid], Lc[cstart(w - u) + u + tid], s);
        }
        int ad = cstart(w) + tid;
        a = Lc[ad] + b0 + __log2f(s);
        Lc[ad] = a;
        if (tid == 0 && w == lenv) *sres = a;
    }
    float m = a;
    for (int d = 32; d; d >>= 1) m = fmaxf(m, __shfl_xor(m, d));
    if (lane == 0) swm[wave] = m;
    __syncthreads();
    float cmw = swm[0];
#pragma unroll
    for (int i = 1; i < 16; ++i) cmw = fmaxf(cmw, swm[i]);
    if (tid < E) {
        int ad = cstart(w) + tid;
        Lc[ad] = fexp2(Lc[ad] - cmw);
    }
    if (tid == 0) cm[w] = cmw;
    __syncthreads();
}

template <bool USE_LDS>
__global__ __launch_bounds__(1024) void cyk_kernel(
    const float* __restrict__ logits,     // [B,N,N,2] f32
    const int* __restrict__ spans_ind,    // [B,N,N] i32
    const void* __restrict__ maskspan,    // [B,N,N] bool (byte or i32)
    const void* __restrict__ span_mask,   // [B,N,N] bool
    float* __restrict__ ws) {
    extern __shared__ float lds[];
    const int c = blockIdx.x;
    const int b = c >> 1;
    const int t = c & 1;
    const int tid = threadIdx.x;
    const int wave = tid >> 6, lane = tid & 63;

    float* __restrict__ Lc = USE_LDS ? lds : (ws + FB_OFF + (size_t)c * LDSF);
    float* __restrict__ cm = Lc + CHARTF;
    float* __restrict__ scr = Lc + SCR_OFF;

    __shared__ int s_len;
    __shared__ int s_isb;
    __shared__ float s_wmax[16];
    __shared__ float s_res;
    if (tid == 0) {
        s_len = 0;
        s_res = K2f * NEGV;
        unsigned probe = *(const unsigned*)maskspan;
        s_isb = (probe > 1u) ? 1 : 0;  // byte-packed bools -> 0x01010101
    }
    __syncthreads();
    const int isb = s_isb;

    // lens[b] = sum_j maskspan[b,0,j]
    if (tid < NN) {
        size_t off = (size_t)b * NN * NN + tid;
        int v = isb ? (((const unsigned char*)maskspan)[off] ? 1 : 0)
                    : (((const int*)maskspan)[off] ? 1 : 0);
        atomicAdd(&s_len, v);
    }

    // one-time D-fill: chart col v = j-i+1 holds K2f * D(i, v) until level v
    for (int it = 0; it < 64; ++it) {
        int f = (it << 10) + tid;            // over the (i, j) square
        int i = f >> 8, j = f & 255;
        if (j >= i) {
            float sc = score_at(logits, spans_ind, span_mask, isb, t, b, i, j);
            Lc[cstart(j - i + 1) + i] = K2f * sc;
        }
    }
    __syncthreads();
    const int lenv = s_len;

    // level 1: convert col 1 (= A[:,1]) to X with exact cmax[1]
    {
        float a = (tid < NN) ? Lc[tid] : NEGB;
        if (tid == 0 && lenv == 1) s_res = a;
        float m = a;
        for (int d = 32; d; d >>= 1) m = fmaxf(m, __shfl_xor(m, d));
        if (lane == 0) s_wmax[wave] = m;
        __syncthreads();
        float c1 = s_wmax[0];
#pragma unroll
        for (int i = 1; i < 16; ++i) c1 = fmaxf(c1, s_wmax[i]);
        if (tid < NN) Lc[tid] = fexp2(a - c1);
        if (tid == 0) cm[1] = c1;
    }
    __syncthreads();

    for (int w = 2; w <= 5; ++w)
        level_direct(Lc, cm, s_wmax, &s_res, w, tid, wave, lane, lenv);
    for (int w = 6; w <= 64; w += 2)
        level_pair<4>(Lc, scr, cm, s_wmax, &s_res, w, tid, wave, lane, lenv);
    for (int w = 66; w <= 128; w += 2)
        level_pair<3>(Lc, scr, cm, s_wmax, &s_res, w, tid, wave, lane, lenv);
    for (int w = 130; w <= 192; w += 2)
        level_pair<2>(Lc, scr, cm, s_wmax, &s_res, w, tid, wave, lane, lenv);
    for (int w = 194; w <= NN; ++w)
        level_small(Lc, scr, cm, &s_res, w, tid, wave, lane, lenv);

    if (tid == 0) {
        int len = s_len;
        float rres = (len >= 1) ? (s_res * LN2f) : NEGV;
        ws[RES_OFF + c] = rres;
        if (t == 0) ws[LEN_OFF + b] = (float)len;
    }
}

__global__ __launch_bounds__(64) void finish_kernel(const float* __restrict__ ws,
                                                    float* __restrict__ out) {
    int b = threadIdx.x;  // 0..63
    float diff = ws[RES_OFF + 2 * b + 1] - ws[RES_OFF + 2 * b];
    float len  = ws[LEN_OFF + b];
    for (int d = 32; d > 0; d >>= 1) {
        diff += __shfl_xor(diff, d);
        len  += __shfl_xor(len, d);
    }
    if (b == 0) out[0] = diff / len;
}

extern "C" void kernel_launch(void* const* d_in, const int* in_sizes, int n_in,
                              void* d_out, int out_size, void* d_ws, size_t ws_size,
                              hipStream_t stream) {
    const float* logits    = (const float*)d_in[0];
    const int*   spans_ind = (const int*)d_in[1];
    const void*  maskspan  = d_in[2];
    const void*  span_mask = d_in[3];
    float* ws = (float*)d_ws;

    const size_t shbytes = (size_t)LDSF * sizeof(float);  // 149008 B
    hipError_t e = hipFuncSetAttribute(
        reinterpret_cast<const void*>(&cyk_kernel<true>),
        hipFuncAttributeMaxDynamicSharedMemorySize, (int)shbytes);
    if (e == hipSuccess) {
        hipLaunchKernelGGL(cyk_kernel<true>, dim3(NCHART), dim3(1024), shbytes,
                           stream, logits, spans_ind, maskspan, span_mask, ws);
    } else {
        hipLaunchKernelGGL(cyk_kernel<false>, dim3(NCHART), dim3(1024), 0,
                           stream, logits, spans_ind, maskspan, span_mask, ws);
    }
    hipLaunchKernelGGL(finish_kernel, dim3(1), dim3(64), 0, stream,
                       ws, (float*)d_out);
}

// Round 4
// 617.827 us; speedup vs baseline: 1.0999x; 1.0999x over previous
//
#include <hip/hip_runtime.h>

// TreecrfLossSRL: inside algorithm, B=64, N=256. Two CYK charts per batch
// (ob / allv) -> scalar (logz - marg).sum()/denom.
//
// LINEAR-DOMAIN chart with per-column scalar scale (exact cmax, r3-proven):
// chart col v stores X[v][i] = 2^(A[i,v] - cmax[v]). Level-w interior term =
// s_u * X[u][i] * X[w-u][i+u], s_u = 2^(cm[u]+cm[w-u]-b) wave-uniform ->
// hot loop is pure mul+fma.
//
// r3 -> r4: GROUP-OF-8 schedule to kill phase overhead (r3: ~700 barrier
// phases x ~850 cyc dominated the 1.44M-cycle block). Per group W..W+7:
//  BULK (16 waves, 2/level): interior terms u in [g+1, W-1] (both cols
//    predate the group) -> 2 slot-partials per level. ONE barrier.
//  CHAIN (wave 0, barrier-free): levels finalized sequentially; same-wave
//    LDS ops are in-order, so level W+g reads cols W..W+g-1 written moments
//    earlier by this wave. Per level: sum 2 slots, fold 2g border terms with
//    base-rescale (F_hi-fold pattern), log2, intra-wave shfl cmax (exact,
//    no cross-wave barrier), convert to X, write col + cm. ONE barrier.
// Barriers: ~700 -> ~85. Border overhead: G(G-1)=56 terms/entry/group (~5%).
// All chart/scr accesses stride-1 across lanes (conflict-free skeleton).

#define NN 256
#define BATCH 64
#define NCHART (2 * BATCH)
#define NEGV -1000000000.0f
#define NEGB -1.0e30f
#define K2f 1.4426950408889634f   /* log2(e) */
#define LN2f 0.6931471805599453f

#define CHARTF 32896                   /* triangular chart, no padding */
#define CMAXF 260                      /* cmax[257] + pad */
#define BB_OFF (CHARTF + CMAXF)        /* per-group bases, 16 floats */
#define SCR_OFF (BB_OFF + 16)
#define SCRF 3952                      /* 16 slots x ES, ES <= 247 */
#define LDSF (SCR_OFF + SCRF)          /* 37124 floats = 148496 B */

#define RES_OFF ((size_t)16)
#define LEN_OFF ((size_t)(16 + NCHART))
#define FB_OFF  ((size_t)(16 + NCHART + BATCH + 16))

__device__ __forceinline__ float fexp2(float x) {
#if __has_builtin(__builtin_amdgcn_exp2f)
    return __builtin_amdgcn_exp2f(x);
#else
    return exp2f(x);
#endif
}

// column start (floats) for width v, v in 1..256
__device__ __forceinline__ int cstart(int v) {
    return 257 * (v - 1) - ((v * (v - 1)) >> 1);
}

// natural-log score at span [i, j] for type t (0 = ob/constrained, 1 = allv)
__device__ __forceinline__ float score_at(const float* __restrict__ logits,
                                          const int* __restrict__ spans_ind,
                                          const void* __restrict__ span_mask,
                                          int isb, int t, int b, int i, int j) {
    size_t sidx = ((size_t)b * NN + i) * NN + j;
    float l0 = logits[2 * sidx];
    float l1 = logits[2 * sidx + 1];
    if (t) {
        float mx = fmaxf(l0, l1), mn = fminf(l0, l1);
        return mx + log1pf(__expf(mn - mx));
    } else {
        bool sind = (spans_ind[sidx] == 2);
        bool sm = isb ? (((const unsigned char*)span_mask)[sidx] != 0)
                      : (((const int*)span_mask)[sidx] != 0);
        float s0 = (sm || sind)  ? NEGV : l0;
        float s1 = (sm || !sind) ? NEGV : l1;
        float mx = fmaxf(s0, s1), mn = fminf(s0, s1);
        return mx + log1pf(__expf(mn - mx));
    }
}

// group of 8 levels W..W+7; KK = ceil((257-W)/64)
template <int KK>
__device__ __forceinline__ void group8(
    float* __restrict__ Lc, float* __restrict__ scr, float* __restrict__ cm,
    float* __restrict__ bbuf, float* __restrict__ sres,
    int W, int tid, int wave, int lane, int lenv) {
    const int ES = 257 - W;   // slot pitch = group max E

    // ---------------- BULK: interior terms, 2 waves per level ----------
    {
        const int g = wave >> 1;
        const int half = wave & 1;
        const int L = W + g;
        if (L <= 256) {
            const int E = 257 - L;
            // base over interior pairs (all cols pre-group, cm known)
            float b = NEGB;
            for (int u = g + 1 + lane; u <= W - 1; u += 64)
                b = fmaxf(b, cm[u] + cm[L - u]);
#pragma unroll
            for (int d = 32; d; d >>= 1) b = fmaxf(b, __shfl_xor(b, d));
            if (lane == 0 && half == 0) bbuf[g] = b;

            const int n_int = W - 1 - g;          // interior u-count
            const int h0 = (n_int + 1) >> 1;
            const int ua = (half == 0) ? (g + 1) : (g + 1 + h0);
            const int ub = (half == 0) ? (g + h0) : (W - 1);  // inclusive

            float acc[KK];
#pragma unroll
            for (int k = 0; k < KK; ++k) acc[k] = 0.f;

            if (ua <= ub) {
                int u = ua, v = L - ua;
                int la = cstart(u) + lane;
                int ra = cstart(v) + u + lane;
                int A = 257 - u, B = 257 - v;
#pragma unroll 2
                for (; u <= ub; ++u) {
                    float su = fexp2(cm[u] + cm[L - u] - b);
#pragma unroll
                    for (int k = 0; k < KK; ++k)
                        acc[k] = fmaf(su * Lc[la + 64 * k],
                                      Lc[ra + 64 * k], acc[k]);
                    la += A; A -= 1;
                    ra -= B; B += 1;
                }
            }
#pragma unroll
            for (int k = 0; k < KK; ++k) {
                int ge = lane + 64 * k;
                if (ge < E) scr[wave * ES + ge] = acc[k];
            }
        }
    }
    __syncthreads();   // G1: slots + bases ready

    // ---------------- CHAIN: wave 0 finalizes 8 levels, no barriers ----
    if (wave == 0) {
        for (int gg = 0; gg < 8; ++gg) {
            const int L = W + gg;
            if (L > 256) break;
            const int E = 257 - L;
            float b = bbuf[gg];

            float s[KK];
#pragma unroll
            for (int k = 0; k < KK; ++k) {
                int ge = lane + 64 * k;
                s[k] = (ge < E) ? scr[(2 * gg) * ES + ge] +
                                  scr[(2 * gg + 1) * ES + ge]
                                : 0.f;
            }

            // border pairs j=1..gg use in-group cols L-j (chain-written)
            float bp = NEGB;
            for (int j = 1; j <= gg; ++j)
                bp = fmaxf(bp, cm[j] + cm[L - j]);
            float b2 = fmaxf(b, bp);
            {
                float sc = fexp2(b - b2);
#pragma unroll
                for (int k = 0; k < KK; ++k) s[k] *= sc;
            }
            for (int j = 1; j <= gg; ++j) {
                float pj = fexp2(cm[j] + cm[L - j] - b2);
                const int cj = cstart(j), cl = cstart(L - j);
#pragma unroll
                for (int k = 0; k < KK; ++k) {
                    int ge = lane + 64 * k;
                    if (ge < E) {
                        float tt = Lc[cj + ge] * Lc[cl + ge + j] +
                                   Lc[cl + ge] * Lc[cj + ge + (L - j)];
                        s[k] = fmaf(pj, tt, s[k]);
                    }
                }
            }

            // finalize: a = D + b2 + log2(s); exact cmax intra-wave; X out
            float xa[KK];
            float m = NEGB;
#pragma unroll
            for (int k = 0; k < KK; ++k) {
                int ge = lane + 64 * k;
                float av = NEGB;
                if (ge < E) av = Lc[cstart(L) + ge] + b2 + __log2f(s[k]);
                xa[k] = av;
                m = fmaxf(m, av);
            }
#pragma unroll
            for (int d = 32; d; d >>= 1) m = fmaxf(m, __shfl_xor(m, d));
#pragma unroll
            for (int k = 0; k < KK; ++k) {
                int ge = lane + 64 * k;
                if (ge < E) Lc[cstart(L) + ge] = fexp2(xa[k] - m);
            }
            if (lane == 0) {
                cm[L] = m;
                if (L == lenv) *sres = xa[0];
            }
        }
    }
    __syncthreads();   // G2: group columns + cm final
}

// direct path for w in [2,9]: each thread does its entry's full sum
__device__ __forceinline__ void level_direct(
    float* __restrict__ Lc, float* __restrict__ cm,
    float* __restrict__ swm, float* __restrict__ sres,
    int w, int tid, int wave, int lane, int lenv) {
    const int E = NN + 1 - w;
    float a = NEGB;
    if (tid < E) {
        float b0 = NEGB;
        for (int u = 1; u <= w - 1; ++u) b0 = fmaxf(b0, cm[u] + cm[w - u]);
        float s = 0.f;
        for (int u = 1; u <= w - 1; ++u) {
            float su = fexp2(cm[u] + cm[w - u] - b0);
            s = fmaf(su * Lc[cstart(u) + tid], Lc[cstart(w - u) + u + tid], s);
        }
        int ad = cstart(w) + tid;
        a = Lc[ad] + b0 + __log2f(s);
        Lc[ad] = a;
        if (tid == 0 && w == lenv) *sres = a;
    }
    float m = a;
    for (int d = 32; d; d >>= 1) m = fmaxf(m, __shfl_xor(m, d));
    if (lane == 0) swm[wave] = m;
    __syncthreads();
    float cmw = swm[0];
#pragma unroll
    for (int i = 1; i < 16; ++i) cmw = fmaxf(cmw, swm[i]);
    if (tid < E) {
        int ad = cstart(w) + tid;
        Lc[ad] = fexp2(Lc[ad] - cmw);
    }
    if (tid == 0) cm[w] = cmw;
    __syncthreads();
}

template <bool USE_LDS>
__global__ __launch_bounds__(1024) void cyk_kernel(
    const float* __restrict__ logits,     // [B,N,N,2] f32
    const int* __restrict__ spans_ind,    // [B,N,N] i32
    const void* __restrict__ maskspan,    // [B,N,N] bool (byte or i32)
    const void* __restrict__ span_mask,   // [B,N,N] bool
    float* __restrict__ ws) {
    extern __shared__ float lds[];
    const int c = blockIdx.x;
    const int b = c >> 1;
    const int t = c & 1;
    const int tid = threadIdx.x;
    const int wave = tid >> 6, lane = tid & 63;

    float* __restrict__ Lc = USE_LDS ? lds : (ws + FB_OFF + (size_t)c * LDSF);
    float* __restrict__ cm = Lc + CHARTF;
    float* __restrict__ bbuf = Lc + BB_OFF;
    float* __restrict__ scr = Lc + SCR_OFF;

    __shared__ int s_len;
    __shared__ int s_isb;
    __shared__ float s_wmax[16];
    __shared__ float s_res;
    if (tid == 0) {
        s_len = 0;
        s_res = K2f * NEGV;
        unsigned probe = *(const unsigned*)maskspan;
        s_isb = (probe > 1u) ? 1 : 0;  // byte-packed bools -> 0x01010101
    }
    __syncthreads();
    const int isb = s_isb;

    // lens[b] = sum_j maskspan[b,0,j]
    if (tid < NN) {
        size_t off = (size_t)b * NN * NN + tid;
        int v = isb ? (((const unsigned char*)maskspan)[off] ? 1 : 0)
                    : (((const int*)maskspan)[off] ? 1 : 0);
        atomicAdd(&s_len, v);
    }

    // one-time D-fill: chart col v = j-i+1 holds K2f * D(i, v) until level v
    for (int it = 0; it < 64; ++it) {
        int f = (it << 10) + tid;            // over the (i, j) square
        int i = f >> 8, j = f & 255;
        if (j >= i) {
            float sc = score_at(logits, spans_ind, span_mask, isb, t, b, i, j);
            Lc[cstart(j - i + 1) + i] = K2f * sc;
        }
    }
    __syncthreads();
    const int lenv = s_len;

    // level 1: convert col 1 (= A[:,1]) to X with exact cmax[1]
    {
        float a = (tid < NN) ? Lc[tid] : NEGB;
        if (tid == 0 && lenv == 1) s_res = a;
        float m = a;
        for (int d = 32; d; d >>= 1) m = fmaxf(m, __shfl_xor(m, d));
        if (lane == 0) s_wmax[wave] = m;
        __syncthreads();
        float c1 = s_wmax[0];
#pragma unroll
        for (int i = 1; i < 16; ++i) c1 = fmaxf(c1, s_wmax[i]);
        if (tid < NN) Lc[tid] = fexp2(a - c1);
        if (tid == 0) cm[1] = c1;
    }
    __syncthreads();

    for (int w = 2; w <= 9; ++w)
        level_direct(Lc, cm, s_wmax, &s_res, w, tid, wave, lane, lenv);
    for (int W = 10; W <= 58; W += 8)
        group8<4>(Lc, scr, cm, bbuf, &s_res, W, tid, wave, lane, lenv);
    for (int W = 66; W <= 122; W += 8)
        group8<3>(Lc, scr, cm, bbuf, &s_res, W, tid, wave, lane, lenv);
    for (int W = 130; W <= 186; W += 8)
        group8<2>(Lc, scr, cm, bbuf, &s_res, W, tid, wave, lane, lenv);
    for (int W = 194; W <= 250; W += 8)
        group8<1>(Lc, scr, cm, bbuf, &s_res, W, tid, wave, lane, lenv);

    if (tid == 0) {
        int len = s_len;
        float rres = (len >= 1) ? (s_res * LN2f) : NEGV;
        ws[RES_OFF + c] = rres;
        if (t == 0) ws[LEN_OFF + b] = (float)len;
    }
}

__global__ __launch_bounds__(64) void finish_kernel(const float* __restrict__ ws,
                                                    float* __restrict__ out) {
    int b = threadIdx.x;  // 0..63
    float diff = ws[RES_OFF + 2 * b + 1] - ws[RES_OFF + 2 * b];
    float len  = ws[LEN_OFF + b];
    for (int d = 32; d > 0; d >>= 1) {
        diff += __shfl_xor(diff, d);
        len  += __shfl_xor(len, d);
    }
    if (b == 0) out[0] = diff / len;
}

extern "C" void kernel_launch(void* const* d_in, const int* in_sizes, int n_in,
                              void* d_out, int out_size, void* d_ws, size_t ws_size,
                              hipStream_t stream) {
    const float* logits    = (const float*)d_in[0];
    const int*   spans_ind = (const int*)d_in[1];
    const void*  maskspan  = d_in[2];
    const void*  span_mask = d_in[3];
    float* ws = (float*)d_ws;

    const size_t shbytes = (size_t)LDSF * sizeof(float);  // 148496 B
    hipError_t e = hipFuncSetAttribute(
        reinterpret_cast<const void*>(&cyk_kernel<true>),
        hipFuncAttributeMaxDynamicSharedMemorySize, (int)shbytes);
    if (e == hipSuccess) {
        hipLaunchKernelGGL(cyk_kernel<true>, dim3(NCHART), dim3(1024), shbytes,
                           stream, logits, spans_ind, maskspan, span_mask, ws);
    } else {
        hipLaunchKernelGGL(cyk_kernel<false>, dim3(NCHART), dim3(1024), 0,
                           stream, logits, spans_ind, maskspan, span_mask, ws);
    }
    hipLaunchKernelGGL(finish_kernel, dim3(1), dim3(64), 0, stream,
                       ws, (float*)d_out);
}

// Round 5
// 543.203 us; speedup vs baseline: 1.2510x; 1.1374x over previous
//
#include <hip/hip_runtime.h>

// TreecrfLossSRL: inside algorithm, B=64, N=256. Two CYK charts per batch
// (ob / allv) -> scalar (logz - marg).sum()/denom.
//
// LINEAR-DOMAIN chart with per-column scalar scale (exact cmax):
// col v stores X[v][i] = 2^(A[i,v] - cm[v]). Interior term of level L =
// 2^(cm[u]+cm[L-u]-b) * X[u][i] * X[L-u][i+u]  -> pure mul+fma hot loop.
//
// r4 -> r5: the serial per-group chain (wave 0 finalizing 8 levels back to
// back, ~2.4K cyc/level of dependent-LDS latency) was ~40% of the kernel.
// Now PIPELINED: wave g finalizes level W+g, synchronized via LDS FLAGS
// (producer: col writes + cm -> __threadfence_block -> volatile flag store;
// consumer: volatile poll + s_sleep -> compiler barrier -> reads). Border
// pairs (j, L-j), j=g..1, are folded with an online rescale in flag-arrival
// order (col W lands first). Exact cmax kept (bound-based scales compound
// slack over the 255-deep recursion -> underflow). Bulk phase = r4 verbatim.
// Barriers: 2 per group (~70 total). Chain spine ~500-700 cyc/level.

#define NN 256
#define BATCH 64
#define NCHART (2 * BATCH)
#define NEGV -1000000000.0f
#define NEGB -1.0e30f
#define K2f 1.4426950408889634f   /* log2(e) */
#define LN2f 0.6931471805599453f

#define CHARTF 32896                   /* triangular chart, no padding */
#define CMAXF 260                      /* cmax[257] + pad */
#define BB_OFF (CHARTF + CMAXF)        /* per-group bases, 16 floats */
#define FLG_OFF (BB_OFF + 16)          /* 257 int flags (+pad) */
#define SCR_OFF (FLG_OFF + 260)
#define SCRF 3952                      /* 16 slots x ES, ES <= 247 */
#define LDSF (SCR_OFF + SCRF)          /* 37384 floats = 149536 B */

#define RES_OFF ((size_t)16)
#define LEN_OFF ((size_t)(16 + NCHART))
#define FB_OFF  ((size_t)(16 + NCHART + BATCH + 16))

__device__ __forceinline__ float fexp2(float x) {
#if __has_builtin(__builtin_amdgcn_exp2f)
    return __builtin_amdgcn_exp2f(x);
#else
    return exp2f(x);
#endif
}

// column start (floats) for width v, v in 1..256
__device__ __forceinline__ int cstart(int v) {
    return 257 * (v - 1) - ((v * (v - 1)) >> 1);
}

// natural-log score at span [i, j] for type t (0 = ob/constrained, 1 = allv)
__device__ __forceinline__ float score_at(const float* __restrict__ logits,
                                          const int* __restrict__ spans_ind,
                                          const void* __restrict__ span_mask,
                                          int isb, int t, int b, int i, int j) {
    size_t sidx = ((size_t)b * NN + i) * NN + j;
    float l0 = logits[2 * sidx];
    float l1 = logits[2 * sidx + 1];
    if (t) {
        float mx = fmaxf(l0, l1), mn = fminf(l0, l1);
        return mx + log1pf(__expf(mn - mx));
    } else {
        bool sind = (spans_ind[sidx] == 2);
        bool sm = isb ? (((const unsigned char*)span_mask)[sidx] != 0)
                      : (((const int*)span_mask)[sidx] != 0);
        float s0 = (sm || sind)  ? NEGV : l0;
        float s1 = (sm || !sind) ? NEGV : l1;
        float mx = fmaxf(s0, s1), mn = fminf(s0, s1);
        return mx + log1pf(__expf(mn - mx));
    }
}

// group of 8 levels W..W+7; KK = ceil((257-W)/64)
template <int KK>
__device__ __forceinline__ void group8(
    float* __restrict__ Lc, float* __restrict__ scr, float* __restrict__ cm,
    float* __restrict__ bbuf, int* flg, float* __restrict__ sres,
    int W, int tid, int wave, int lane, int lenv) {
    const int ES = 257 - W;   // slot pitch = group max E

    // ---------------- BULK: interior terms, 2 waves per level ----------
    {
        const int g = wave >> 1;
        const int half = wave & 1;
        const int L = W + g;
        if (L <= 256) {
            const int E = 257 - L;
            // base over interior pairs (all cols pre-group, cm known)
            float b = NEGB;
            for (int u = g + 1 + lane; u <= W - 1; u += 64)
                b = fmaxf(b, cm[u] + cm[L - u]);
#pragma unroll
            for (int d = 32; d; d >>= 1) b = fmaxf(b, __shfl_xor(b, d));
            if (lane == 0 && half == 0) bbuf[g] = b;

            const int n_int = W - 1 - g;          // interior u-count
            const int h0 = (n_int + 1) >> 1;
            const int ua = (half == 0) ? (g + 1) : (g + 1 + h0);
            const int ub = (half == 0) ? (g + h0) : (W - 1);  // inclusive

            float acc[KK];
#pragma unroll
            for (int k = 0; k < KK; ++k) acc[k] = 0.f;

            if (ua <= ub) {
                int u = ua, v = L - ua;
                int la = cstart(u) + lane;
                int ra = cstart(v) + u + lane;
                int A = 257 - u, B = 257 - v;
#pragma unroll 2
                for (; u <= ub; ++u) {
                    float su = fexp2(cm[u] + cm[L - u] - b);
#pragma unroll
                    for (int k = 0; k < KK; ++k)
                        acc[k] = fmaf(su * Lc[la + 64 * k],
                                      Lc[ra + 64 * k], acc[k]);
                    la += A; A -= 1;
                    ra -= B; B += 1;
                }
            }
#pragma unroll
            for (int k = 0; k < KK; ++k) {
                int ge = lane + 64 * k;
                if (ge < E) scr[wave * ES + ge] = acc[k];
            }
        }
    }
    __syncthreads();   // G1: slots + bases ready

    // ------- CHAIN (pipelined): wave g finalizes level W+g, flag-synced ----
    if (wave < 8) {
        const int g = wave;
        const int L = W + g;
        if (L <= 256) {
            const int E = 257 - L;
            float m = bbuf[g];

            float s[KK];
#pragma unroll
            for (int k = 0; k < KK; ++k) {
                int ge = lane + 64 * k;
                s[k] = (ge < E) ? scr[(2 * g) * ES + ge] +
                                  scr[(2 * g + 1) * ES + ge]
                                : 0.f;
            }

            // border pairs in flag-arrival order: j=g (col W) .. j=1 (col L-1)
            for (int j = g; j >= 1; --j) {
                const int v = L - j;
                while (((volatile int*)flg)[v] == 0)
                    __builtin_amdgcn_s_sleep(1);
                asm volatile("" ::: "memory");   // acquire: no hoist above poll
                float pm = cm[j] + cm[v];
                float nm = fmaxf(m, pm);
                float sc = fexp2(m - nm), pj = fexp2(pm - nm);
                const int cj = cstart(j), cl = cstart(v);
#pragma unroll
                for (int k = 0; k < KK; ++k) {
                    int ge = lane + 64 * k;
                    if (ge < E) {
                        float tt = Lc[cj + ge] * Lc[cl + ge + j] +
                                   Lc[cl + ge] * Lc[cj + ge + v];
                        s[k] = fmaf(s[k], sc, pj * tt);
                    }
                }
                m = nm;
            }

            // finalize: a = D + m + log2(s); exact cmax intra-wave; X out
            float xa[KK];
            float mx = NEGB;
#pragma unroll
            for (int k = 0; k < KK; ++k) {
                int ge = lane + 64 * k;
                float av = NEGB;
                if (ge < E) av = Lc[cstart(L) + ge] + m + __log2f(s[k]);
                xa[k] = av;
                mx = fmaxf(mx, av);
            }
#pragma unroll
            for (int d = 32; d; d >>= 1) mx = fmaxf(mx, __shfl_xor(mx, d));
#pragma unroll
            for (int k = 0; k < KK; ++k) {
                int ge = lane + 64 * k;
                if (ge < E) Lc[cstart(L) + ge] = fexp2(xa[k] - mx);
            }
            if (lane == 0) {
                cm[L] = mx;
                if (L == lenv) *sres = xa[0];
            }
            __threadfence_block();               // release: drain col + cm
            asm volatile("" ::: "memory");
            if (lane == 0) ((volatile int*)flg)[L] = 1;
        }
    }
    __syncthreads();   // G2: group columns + cm final
}

// direct path for w in [2,9]: each thread does its entry's full sum
__device__ __forceinline__ void level_direct(
    float* __restrict__ Lc, float* __restrict__ cm,
    float* __restrict__ swm, float* __restrict__ sres,
    int w, int tid, int wave, int lane, int lenv) {
    const int E = NN + 1 - w;
    float a = NEGB;
    if (tid < E) {
        float b0 = NEGB;
        for (int u = 1; u <= w - 1; ++u) b0 = fmaxf(b0, cm[u] + cm[w - u]);
        float s = 0.f;
        for (int u = 1; u <= w - 1; ++u) {
            float su = fexp2(cm[u] + cm[w - u] - b0);
            s = fmaf(su * Lc[cstart(u) + tid], Lc[cstart(w - u) + u + tid], s);
        }
        int ad = cstart(w) + tid;
        a = Lc[ad] + b0 + __log2f(s);
        Lc[ad] = a;
        if (tid == 0 && w == lenv) *sres = a;
    }
    float m = a;
    for (int d = 32; d; d >>= 1) m = fmaxf(m, __shfl_xor(m, d));
    if (lane == 0) swm[wave] = m;
    __syncthreads();
    float cmw = swm[0];
#pragma unroll
    for (int i = 1; i < 16; ++i) cmw = fmaxf(cmw, swm[i]);
    if (tid < E) {
        int ad = cstart(w) + tid;
        Lc[ad] = fexp2(Lc[ad] - cmw);
    }
    if (tid == 0) cm[w] = cmw;
    __syncthreads();
}

template <bool USE_LDS>
__global__ __launch_bounds__(1024) void cyk_kernel(
    const float* __restrict__ logits,     // [B,N,N,2] f32
    const int* __restrict__ spans_ind,    // [B,N,N] i32
    const void* __restrict__ maskspan,    // [B,N,N] bool (byte or i32)
    const void* __restrict__ span_mask,   // [B,N,N] bool
    float* __restrict__ ws) {
    extern __shared__ float lds[];
    const int c = blockIdx.x;
    const int b = c >> 1;
    const int t = c & 1;
    const int tid = threadIdx.x;
    const int wave = tid >> 6, lane = tid & 63;

    float* __restrict__ Lc = USE_LDS ? lds : (ws + FB_OFF + (size_t)c * LDSF);
    float* __restrict__ cm = Lc + CHARTF;
    float* __restrict__ bbuf = Lc + BB_OFF;
    int* flg = (int*)(Lc + FLG_OFF);
    float* __restrict__ scr = Lc + SCR_OFF;

    __shared__ int s_len;
    __shared__ int s_isb;
    __shared__ float s_wmax[16];
    __shared__ float s_res;
    if (tid == 0) {
        s_len = 0;
        s_res = K2f * NEGV;
        unsigned probe = *(const unsigned*)maskspan;
        s_isb = (probe > 1u) ? 1 : 0;  // byte-packed bools -> 0x01010101
    }
    if (tid < 260) flg[tid] = 0;       // per-level publish flags (set once)
    __syncthreads();
    const int isb = s_isb;

    // lens[b] = sum_j maskspan[b,0,j]
    if (tid < NN) {
        size_t off = (size_t)b * NN * NN + tid;
        int v = isb ? (((const unsigned char*)maskspan)[off] ? 1 : 0)
                    : (((const int*)maskspan)[off] ? 1 : 0);
        atomicAdd(&s_len, v);
    }

    // one-time D-fill: chart col v = j-i+1 holds K2f * D(i, v) until level v
    for (int it = 0; it < 64; ++it) {
        int f = (it << 10) + tid;            // over the (i, j) square
        int i = f >> 8, j = f & 255;
        if (j >= i) {
            float sc = score_at(logits, spans_ind, span_mask, isb, t, b, i, j);
            Lc[cstart(j - i + 1) + i] = K2f * sc;
        }
    }
    __syncthreads();
    const int lenv = s_len;

    // level 1: convert col 1 (= A[:,1]) to X with exact cmax[1]
    {
        float a = (tid < NN) ? Lc[tid] : NEGB;
        if (tid == 0 && lenv == 1) s_res = a;
        float m = a;
        for (int d = 32; d; d >>= 1) m = fmaxf(m, __shfl_xor(m, d));
        if (lane == 0) s_wmax[wave] = m;
        __syncthreads();
        float c1 = s_wmax[0];
#pragma unroll
        for (int i = 1; i < 16; ++i) c1 = fmaxf(c1, s_wmax[i]);
        if (tid < NN) Lc[tid] = fexp2(a - c1);
        if (tid == 0) cm[1] = c1;
    }
    __syncthreads();

    for (int w = 2; w <= 9; ++w)
        level_direct(Lc, cm, s_wmax, &s_res, w, tid, wave, lane, lenv);
    for (int W = 10; W <= 58; W += 8)
        group8<4>(Lc, scr, cm, bbuf, flg, &s_res, W, tid, wave, lane, lenv);
    for (int W = 66; W <= 122; W += 8)
        group8<3>(Lc, scr, cm, bbuf, flg, &s_res, W, tid, wave, lane, lenv);
    for (int W = 130; W <= 186; W += 8)
        group8<2>(Lc, scr, cm, bbuf, flg, &s_res, W, tid, wave, lane, lenv);
    for (int W = 194; W <= 250; W += 8)
        group8<1>(Lc, scr, cm, bbuf, flg, &s_res, W, tid, wave, lane, lenv);

    if (tid == 0) {
        int len = s_len;
        float rres = (len >= 1) ? (s_res * LN2f) : NEGV;
        ws[RES_OFF + c] = rres;
        if (t == 0) ws[LEN_OFF + b] = (float)len;
    }
}

__global__ __launch_bounds__(64) void finish_kernel(const float* __restrict__ ws,
                                                    float* __restrict__ out) {
    int b = threadIdx.x;  // 0..63
    float diff = ws[RES_OFF + 2 * b + 1] - ws[RES_OFF + 2 * b];
    float len  = ws[LEN_OFF + b];
    for (int d = 32; d > 0; d >>= 1) {
        diff += __shfl_xor(diff, d);
        len  += __shfl_xor(len, d);
    }
    if (b == 0) out[0] = diff / len;
}

extern "C" void kernel_launch(void* const* d_in, const int* in_sizes, int n_in,
                              void* d_out, int out_size, void* d_ws, size_t ws_size,
                              hipStream_t stream) {
    const float* logits    = (const float*)d_in[0];
    const int*   spans_ind = (const int*)d_in[1];
    const void*  maskspan  = d_in[2];
    const void*  span_mask = d_in[3];
    float* ws = (float*)d_ws;

    const size_t shbytes = (size_t)LDSF * sizeof(float);  // 149536 B
    hipError_t e = hipFuncSetAttribute(
        reinterpret_cast<const void*>(&cyk_kernel<true>),
        hipFuncAttributeMaxDynamicSharedMemorySize, (int)shbytes);
    if (e == hipSuccess) {
        hipLaunchKernelGGL(cyk_kernel<true>, dim3(NCHART), dim3(1024), shbytes,
                           stream, logits, spans_ind, maskspan, span_mask, ws);
    } else {
        hipLaunchKernelGGL(cyk_kernel<false>, dim3(NCHART), dim3(1024), 0,
                           stream, logits, spans_ind, maskspan, span_mask, ws);
    }
    hipLaunchKernelGGL(finish_kernel, dim3(1), dim3(64), 0, stream,
                       ws, (float*)d_out);
}

// Round 6
// 490.084 us; speedup vs baseline: 1.3866x; 1.1084x over previous
//
#include <hip/hip_runtime.h>

// TreecrfLossSRL: inside algorithm, B=64, N=256. Two CYK charts per batch
// (ob / allv) -> scalar (logz - marg).sum()/denom.
//
// LINEAR-DOMAIN chart with per-column scalar scale (exact cmax):
// col v stores X[v][i] = 2^(A[i,v] - cm[v]). Interior term of level L =
// 2^(cm[u]+cm[L-u]-b) * X[u][i] * X[L-u][i+u]  -> pure mul+fma hot loop.
// Group-of-8 levels; bulk (16 waves, 2/level) + flag-pipelined chain
// (wave g finalizes level W+g; producer: fence + LDS flag; consumer:
// volatile poll) -- r5-proven structure kept verbatim.
//
// r5 -> r6:
//  1) DPP wave reduces (row_shr 1/2/4/8 + row_bcast15/31 + readlane 63)
//     replace __shfl_xor chains (shfl = ds_bpermute on LDS pipe, ~240 cyc
//     dependent; DPP is VALU-speed ~40 cyc). Cuts the chain's per-level
//     publish tail and the bulk base reduce. Poll no longer s_sleeps.
//  2) su-precompute: each bulk wave computes its split-scales
//     su[u] = 2^(cm[u]+cm[L-u]-b) lane-parallel into 1-2 VGPRs up front;
//     inner loop fetches via uniform-index readlane -> no per-u cm LDS
//     reads, no dependent exp2 stall. Inner loop = KK*(2 ds_read+mul+fma).

#define NN 256
#define BATCH 64
#define NCHART (2 * BATCH)
#define NEGV -1000000000.0f
#define NEGB -1.0e30f
#define K2f 1.4426950408889634f   /* log2(e) */
#define LN2f 0.6931471805599453f

#define CHARTF 32896                   /* triangular chart, no padding */
#define CMAXF 260                      /* cmax[257] + pad */
#define BB_OFF (CHARTF + CMAXF)        /* per-group bases, 16 floats */
#define FLG_OFF (BB_OFF + 16)          /* 257 int flags (+pad) */
#define SCR_OFF (FLG_OFF + 260)
#define SCRF 3952                      /* 16 slots x ES, ES <= 247 */
#define LDSF (SCR_OFF + SCRF)          /* 37384 floats = 149536 B */

#define RES_OFF ((size_t)16)
#define LEN_OFF ((size_t)(16 + NCHART))
#define FB_OFF  ((size_t)(16 + NCHART + BATCH + 16))

__device__ __forceinline__ float fexp2(float x) {
#if __has_builtin(__builtin_amdgcn_exp2f)
    return __builtin_amdgcn_exp2f(x);
#else
    return exp2f(x);
#endif
}

// wave64 max reduce via DPP (VALU pipe), result broadcast to all lanes.
// rocPRIM-standard: row_shr 1/2/4/8, row_bcast15 (rows 1,3), row_bcast31
// (rows 2,3); full max lands in lane 63; readlane broadcasts.
__device__ __forceinline__ float wave_max64(float x) {
    int v = __float_as_int(x);
    int s;
    s = __builtin_amdgcn_update_dpp(v, v, 0x111, 0xf, 0xf, false);
    v = __float_as_int(fmaxf(__int_as_float(v), __int_as_float(s)));
    s = __builtin_amdgcn_update_dpp(v, v, 0x112, 0xf, 0xf, false);
    v = __float_as_int(fmaxf(__int_as_float(v), __int_as_float(s)));
    s = __builtin_amdgcn_update_dpp(v, v, 0x114, 0xf, 0xf, false);
    v = __float_as_int(fmaxf(__int_as_float(v), __int_as_float(s)));
    s = __builtin_amdgcn_update_dpp(v, v, 0x118, 0xf, 0xf, false);
    v = __float_as_int(fmaxf(__int_as_float(v), __int_as_float(s)));
    s = __builtin_amdgcn_update_dpp(v, v, 0x142, 0xa, 0xf, false);
    v = __float_as_int(fmaxf(__int_as_float(v), __int_as_float(s)));
    s = __builtin_amdgcn_update_dpp(v, v, 0x143, 0xc, 0xf, false);
    v = __float_as_int(fmaxf(__int_as_float(v), __int_as_float(s)));
    return __int_as_float(__builtin_amdgcn_readlane(v, 63));
}

__device__ __forceinline__ float rlane(float v, int idx) {
    return __int_as_float(__builtin_amdgcn_readlane(__float_as_int(v), idx));
}

// column start (floats) for width v, v in 1..256
__device__ __forceinline__ int cstart(int v) {
    return 257 * (v - 1) - ((v * (v - 1)) >> 1);
}

// natural-log score at span [i, j] for type t (0 = ob/constrained, 1 = allv)
__device__ __forceinline__ float score_at(const float* __restrict__ logits,
                                          const int* __restrict__ spans_ind,
                                          const void* __restrict__ span_mask,
                                          int isb, int t, int b, int i, int j) {
    size_t sidx = ((size_t)b * NN + i) * NN + j;
    float l0 = logits[2 * sidx];
    float l1 = logits[2 * sidx + 1];
    if (t) {
        float mx = fmaxf(l0, l1), mn = fminf(l0, l1);
        return mx + log1pf(__expf(mn - mx));
    } else {
        bool sind = (spans_ind[sidx] == 2);
        bool sm = isb ? (((const unsigned char*)span_mask)[sidx] != 0)
                      : (((const int*)span_mask)[sidx] != 0);
        float s0 = (sm || sind)  ? NEGV : l0;
        float s1 = (sm || !sind) ? NEGV : l1;
        float mx = fmaxf(s0, s1), mn = fminf(s0, s1);
        return mx + log1pf(__expf(mn - mx));
    }
}

// group of 8 levels W..W+7; KK = ceil((257-W)/64)
template <int KK>
__device__ __forceinline__ void group8(
    float* __restrict__ Lc, float* __restrict__ scr, float* __restrict__ cm,
    float* __restrict__ bbuf, int* flg, float* __restrict__ sres,
    int W, int tid, int wave, int lane, int lenv) {
    const int ES = 257 - W;   // slot pitch = group max E

    // ---------------- BULK: interior terms, 2 waves per level ----------
    {
        const int g = wave >> 1;
        const int half = wave & 1;
        const int L = W + g;
        if (L <= 256) {
            const int E = 257 - L;
            // base over full interior range (both halves -> same b)
            float b = NEGB;
            for (int uu = g + 1 + lane; uu <= W - 1; uu += 64)
                b = fmaxf(b, cm[uu] + cm[L - uu]);
            b = wave_max64(b);
            if (lane == 0 && half == 0) bbuf[g] = b;

            const int n_int = W - 1 - g;          // interior u-count
            const int h0 = (n_int + 1) >> 1;
            const int ua = half ? (g + 1 + h0) : (g + 1);
            const int ub = half ? (W - 1) : (g + h0);  // inclusive
            const int R = ub - ua + 1;                 // <= 125

            // split-scales in VGPRs (lane-parallel, readlane'd in the loop)
            float su0, su1 = 0.f;
            {
                int uu = ua + lane;
                int uc = (uu <= ub) ? uu : ub;
                su0 = fexp2(cm[uc] + cm[L - uc] - b);
                if (R > 64) {
                    int uu2 = ua + 64 + lane;
                    int uc2 = (uu2 <= ub) ? uu2 : ub;
                    su1 = fexp2(cm[uc2] + cm[L - uc2] - b);
                }
            }

            float acc[KK];
#pragma unroll
            for (int k = 0; k < KK; ++k) acc[k] = 0.f;

            if (R > 0) {
                int la = cstart(ua) + lane;
                int ra = cstart(L - ua) + ua + lane;
                int A = 257 - ua, B = 257 - (L - ua);
                const int R0 = (R < 64) ? R : 64;
#pragma unroll 2
                for (int idx = 0; idx < R0; ++idx) {
                    float su = rlane(su0, idx);
#pragma unroll
                    for (int k = 0; k < KK; ++k)
                        acc[k] = fmaf(su * Lc[la + 64 * k],
                                      Lc[ra + 64 * k], acc[k]);
                    la += A; A -= 1;
                    ra -= B; B += 1;
                }
#pragma unroll 2
                for (int idx = 64; idx < R; ++idx) {
                    float su = rlane(su1, idx - 64);
#pragma unroll
                    for (int k = 0; k < KK; ++k)
                        acc[k] = fmaf(su * Lc[la + 64 * k],
                                      Lc[ra + 64 * k], acc[k]);
                    la += A; A -= 1;
                    ra -= B; B += 1;
                }
            }
#pragma unroll
            for (int k = 0; k < KK; ++k) {
                int ge = lane + 64 * k;
                if (ge < E) scr[wave * ES + ge] = acc[k];
            }
        }
    }
    __syncthreads();   // G1: slots + bases ready

    // ------- CHAIN (pipelined): wave g finalizes level W+g, flag-synced ----
    if (wave < 8) {
        const int g = wave;
        const int L = W + g;
        if (L <= 256) {
            const int E = 257 - L;
            float m = bbuf[g];

            float s[KK];
#pragma unroll
            for (int k = 0; k < KK; ++k) {
                int ge = lane + 64 * k;
                s[k] = (ge < E) ? scr[(2 * g) * ES + ge] +
                                  scr[(2 * g + 1) * ES + ge]
                                : 0.f;
            }

            // border pairs in flag-arrival order: j=g (col W) .. j=1 (col L-1)
            for (int j = g; j >= 1; --j) {
                const int v = L - j;
                while (((volatile int*)flg)[v] == 0) {}
                asm volatile("" ::: "memory");   // acquire: no hoist above poll
                float pm = cm[j] + cm[v];
                float nm = fmaxf(m, pm);
                float sc = fexp2(m - nm), pj = fexp2(pm - nm);
                const int cj = cstart(j), cl = cstart(v);
#pragma unroll
                for (int k = 0; k < KK; ++k) {
                    int ge = lane + 64 * k;
                    if (ge < E) {
                        float tt = Lc[cj + ge] * Lc[cl + ge + j] +
                                   Lc[cl + ge] * Lc[cj + ge + v];
                        s[k] = fmaf(s[k], sc, pj * tt);
                    }
                }
                m = nm;
            }

            // finalize: a = D + m + log2(s); exact cmax intra-wave; X out
            float xa[KK];
            float mx = NEGB;
#pragma unroll
            for (int k = 0; k < KK; ++k) {
                int ge = lane + 64 * k;
                float av = NEGB;
                if (ge < E) av = Lc[cstart(L) + ge] + m + __log2f(s[k]);
                xa[k] = av;
                mx = fmaxf(mx, av);
            }
            mx = wave_max64(mx);
#pragma unroll
            for (int k = 0; k < KK; ++k) {
                int ge = lane + 64 * k;
                if (ge < E) Lc[cstart(L) + ge] = fexp2(xa[k] - mx);
            }
            if (lane == 0) {
                cm[L] = mx;
                if (L == lenv) *sres = xa[0];
            }
            __threadfence_block();               // release: drain col + cm
            asm volatile("" ::: "memory");
            if (lane == 0) ((volatile int*)flg)[L] = 1;
        }
    }
    __syncthreads();   // G2: group columns + cm final
}

// direct path for w in [2,9]: each thread does its entry's full sum
__device__ __forceinline__ void level_direct(
    float* __restrict__ Lc, float* __restrict__ cm,
    float* __restrict__ swm, float* __restrict__ sres,
    int w, int tid, int wave, int lane, int lenv) {
    const int E = NN + 1 - w;
    float a = NEGB;
    if (tid < E) {
        float b0 = NEGB;
        for (int u = 1; u <= w - 1; ++u) b0 = fmaxf(b0, cm[u] + cm[w - u]);
        float s = 0.f;
        for (int u = 1; u <= w - 1; ++u) {
            float su = fexp2(cm[u] + cm[w - u] - b0);
            s = fmaf(su * Lc[cstart(u) + tid], Lc[cstart(w - u) + u + tid], s);
        }
        int ad = cstart(w) + tid;
        a = Lc[ad] + b0 + __log2f(s);
        Lc[ad] = a;
        if (tid == 0 && w == lenv) *sres = a;
    }
    float m = wave_max64(a);
    if (lane == 0) swm[wave] = m;
    __syncthreads();
    float cmw = swm[0];
#pragma unroll
    for (int i = 1; i < 16; ++i) cmw = fmaxf(cmw, swm[i]);
    if (tid < E) {
        int ad = cstart(w) + tid;
        Lc[ad] = fexp2(Lc[ad] - cmw);
    }
    if (tid == 0) cm[w] = cmw;
    __syncthreads();
}

template <bool USE_LDS>
__global__ __launch_bounds__(1024) void cyk_kernel(
    const float* __restrict__ logits,     // [B,N,N,2] f32
    const int* __restrict__ spans_ind,    // [B,N,N] i32
    const void* __restrict__ maskspan,    // [B,N,N] bool (byte or i32)
    const void* __restrict__ span_mask,   // [B,N,N] bool
    float* __restrict__ ws) {
    extern __shared__ float lds[];
    const int c = blockIdx.x;
    const int b = c >> 1;
    const int t = c & 1;
    const int tid = threadIdx.x;
    const int wave = tid >> 6, lane = tid & 63;

    float* __restrict__ Lc = USE_LDS ? lds : (ws + FB_OFF + (size_t)c * LDSF);
    float* __restrict__ cm = Lc + CHARTF;
    float* __restrict__ bbuf = Lc + BB_OFF;
    int* flg = (int*)(Lc + FLG_OFF);
    float* __restrict__ scr = Lc + SCR_OFF;

    __shared__ int s_len;
    __shared__ int s_isb;
    __shared__ float s_wmax[16];
    __shared__ float s_res;
    if (tid == 0) {
        s_len = 0;
        s_res = K2f * NEGV;
        unsigned probe = *(const unsigned*)maskspan;
        s_isb = (probe > 1u) ? 1 : 0;  // byte-packed bools -> 0x01010101
    }
    if (tid < 260) flg[tid] = 0;       // per-level publish flags (set once)
    __syncthreads();
    const int isb = s_isb;

    // lens[b] = sum_j maskspan[b,0,j]
    if (tid < NN) {
        size_t off = (size_t)b * NN * NN + tid;
        int v = isb ? (((const unsigned char*)maskspan)[off] ? 1 : 0)
                    : (((const int*)maskspan)[off] ? 1 : 0);
        atomicAdd(&s_len, v);
    }

    // one-time D-fill: chart col v = j-i+1 holds K2f * D(i, v) until level v
    for (int it = 0; it < 64; ++it) {
        int f = (it << 10) + tid;            // over the (i, j) square
        int i = f >> 8, j = f & 255;
        if (j >= i) {
            float sc = score_at(logits, spans_ind, span_mask, isb, t, b, i, j);
            Lc[cstart(j - i + 1) + i] = K2f * sc;
        }
    }
    __syncthreads();
    const int lenv = s_len;

    // level 1: convert col 1 (= A[:,1]) to X with exact cmax[1]
    {
        float a = (tid < NN) ? Lc[tid] : NEGB;
        if (tid == 0 && lenv == 1) s_res = a;
        float m = wave_max64(a);
        if (lane == 0) s_wmax[wave] = m;
        __syncthreads();
        float c1 = s_wmax[0];
#pragma unroll
        for (int i = 1; i < 16; ++i) c1 = fmaxf(c1, s_wmax[i]);
        if (tid < NN) Lc[tid] = fexp2(a - c1);
        if (tid == 0) cm[1] = c1;
    }
    __syncthreads();

    for (int w = 2; w <= 9; ++w)
        level_direct(Lc, cm, s_wmax, &s_res, w, tid, wave, lane, lenv);
    for (int W = 10; W <= 58; W += 8)
        group8<4>(Lc, scr, cm, bbuf, flg, &s_res, W, tid, wave, lane, lenv);
    for (int W = 66; W <= 122; W += 8)
        group8<3>(Lc, scr, cm, bbuf, flg, &s_res, W, tid, wave, lane, lenv);
    for (int W = 130; W <= 186; W += 8)
        group8<2>(Lc, scr, cm, bbuf, flg, &s_res, W, tid, wave, lane, lenv);
    for (int W = 194; W <= 250; W += 8)
        group8<1>(Lc, scr, cm, bbuf, flg, &s_res, W, tid, wave, lane, lenv);

    if (tid == 0) {
        int len = s_len;
        float rres = (len >= 1) ? (s_res * LN2f) : NEGV;
        ws[RES_OFF + c] = rres;
        if (t == 0) ws[LEN_OFF + b] = (float)len;
    }
}

__global__ __launch_bounds__(64) void finish_kernel(const float* __restrict__ ws,
                                                    float* __restrict__ out) {
    int b = threadIdx.x;  // 0..63
    float diff = ws[RES_OFF + 2 * b + 1] - ws[RES_OFF + 2 * b];
    float len  = ws[LEN_OFF + b];
    for (int d = 32; d > 0; d >>= 1) {
        diff += __shfl_xor(diff, d);
        len  += __shfl_xor(len, d);
    }
    if (b == 0) out[0] = diff / len;
}

extern "C" void kernel_launch(void* const* d_in, const int* in_sizes, int n_in,
                              void* d_out, int out_size, void* d_ws, size_t ws_size,
                              hipStream_t stream) {
    const float* logits    = (const float*)d_in[0];
    const int*   spans_ind = (const int*)d_in[1];
    const void*  maskspan  = d_in[2];
    const void*  span_mask = d_in[3];
    float* ws = (float*)d_ws;

    const size_t shbytes = (size_t)LDSF * sizeof(float);  // 149536 B
    hipError_t e = hipFuncSetAttribute(
        reinterpret_cast<const void*>(&cyk_kernel<true>),
        hipFuncAttributeMaxDynamicSharedMemorySize, (int)shbytes);
    if (e == hipSuccess) {
        hipLaunchKernelGGL(cyk_kernel<true>, dim3(NCHART), dim3(1024), shbytes,
                           stream, logits, spans_ind, maskspan, span_mask, ws);
    } else {
        hipLaunchKernelGGL(cyk_kernel<false>, dim3(NCHART), dim3(1024), 0,
                           stream, logits, spans_ind, maskspan, span_mask, ws);
    }
    hipLaunchKernelGGL(finish_kernel, dim3(1), dim3(64), 0, stream,
                       ws, (float*)d_out);
}